// Round 1
// baseline (952.947 us; speedup 1.0000x reference)
//
#include <hip/hip_runtime.h>
#include <hip/hip_bf16.h>

// Problem constants (from reference)
#define T_TOK 4096      // SL*BS tokens
#define E_EXP 16
#define TOPK 4
#define HDIM 1024
#define FDIM 2048
#define CAP 1024        // capacity = K*T/E
#define NCOPY (T_TOK*TOPK)

typedef __bf16 bf16x8 __attribute__((ext_vector_type(8)));
typedef __bf16 bf16x4 __attribute__((ext_vector_type(4)));
typedef float  f32x4  __attribute__((ext_vector_type(4)));

// Direct global->LDS DMA, 16B per lane. LDS dest must be wave-uniform base +
// lane*16 — our tid-linear chunk layout satisfies this exactly (m104/m108).
__device__ __forceinline__ void gload_lds16(const __bf16* g, __bf16* l)
{
    __builtin_amdgcn_global_load_lds(
        (__attribute__((address_space(1))) void*)g,
        (__attribute__((address_space(3))) void*)l, 16, 0, 0);
}

// ---------------------------------------------------------------------------
// Router: logits = x @ rw^T + rb ; top-4 (desc, ties->lowest idx) ; softmax.
// One wave per token. Writes expert_weights [T,4], router_scores [E,T], te [T,4].
// ---------------------------------------------------------------------------
__global__ __launch_bounds__(64) void router_kernel(
    const float* __restrict__ x, const float* __restrict__ rw, const float* __restrict__ rb,
    float* __restrict__ ew_out, float* __restrict__ rs_out, int* __restrict__ te_out)
{
    int t = blockIdx.x;
    int lane = threadIdx.x;
    const float* xr = x + (size_t)t * HDIM;
    float xv[16];
#pragma unroll
    for (int i = 0; i < 16; ++i) xv[i] = xr[i * 64 + lane];
    float lg[E_EXP];
#pragma unroll
    for (int e = 0; e < E_EXP; ++e) {
        const float* wrow = rw + (size_t)e * HDIM;
        float s = 0.f;
#pragma unroll
        for (int i = 0; i < 16; ++i) s += xv[i] * wrow[i * 64 + lane];
#pragma unroll
        for (int off = 32; off > 0; off >>= 1) s += __shfl_xor(s, off, 64);
        lg[e] = s + rb[e];
    }
    // top-4, descending, strict '>' keeps lowest index on ties (matches lax.top_k)
    int mask = 0; float vals[4]; int idxs[4];
#pragma unroll
    for (int k = 0; k < 4; ++k) {
        float m = -3.4e38f; int a = 0;
#pragma unroll
        for (int e = 0; e < E_EXP; ++e) {
            bool take = (((mask >> e) & 1) == 0) && (lg[e] > m);
            m = take ? lg[e] : m;
            a = take ? e : a;
        }
        vals[k] = m; idxs[k] = a; mask |= (1 << a);
    }
    float wk[4]; float ssum = 0.f;
#pragma unroll
    for (int k = 0; k < 4; ++k) { wk[k] = __expf(vals[k] - vals[0]); ssum += wk[k]; }
    float inv = 1.f / ssum;
#pragma unroll
    for (int k = 0; k < 4; ++k) wk[k] *= inv;
    if (lane < 4) {
        float wv = 0.f; int iv = 0;
#pragma unroll
        for (int k = 0; k < 4; ++k) if (lane == k) { wv = wk[k]; iv = idxs[k]; }
        ew_out[t * 4 + lane] = wv;
        te_out[t * 4 + lane] = iv;
    }
    if (lane < E_EXP) {
        float v = 0.f;
#pragma unroll
        for (int k = 0; k < 4; ++k) v = (idxs[k] == lane) ? wk[k] : v;
        rs_out[(size_t)lane * T_TOK + t] = v;
    }
}

// ---------------------------------------------------------------------------
// Binning: stable rank-within-expert == stable argsort by expert id.
// Single block; thread owns 64 consecutive copies; chunked histogram + serial
// per-expert exclusive prefix over chunks. slot_tok=-1 marks empty slots.
// ---------------------------------------------------------------------------
__global__ __launch_bounds__(256) void binning_kernel(
    const int* __restrict__ te, const float* __restrict__ ew,
    int* __restrict__ slot_tok, float* __restrict__ slot_w)
{
    __shared__ int cnt[256][17];   // +1 pad: conflict-free columns
    int tid = threadIdx.x;
#pragma unroll
    for (int e = 0; e < E_EXP; ++e) cnt[tid][e] = 0;
    __syncthreads();
    int base = tid * 64;
    for (int i = 0; i < 64; ++i) cnt[tid][te[base + i]]++;
    __syncthreads();
    if (tid < E_EXP) {
        int run = 0;
        for (int t2 = 0; t2 < 256; ++t2) { int v = cnt[t2][tid]; cnt[t2][tid] = run; run += v; }
    }
    __syncthreads();
    for (int s = tid; s < E_EXP * CAP; s += 256) { slot_tok[s] = -1; slot_w[s] = 0.f; }
    __syncthreads();
    for (int i = 0; i < 64; ++i) {
        int idx = base + i;
        int e = te[idx];
        int r = cnt[tid][e]; cnt[tid][e] = r + 1;
        if (r < CAP) { slot_tok[e * CAP + r] = idx >> 2; slot_w[e * CAP + r] = ew[idx]; }
    }
}

// ---------------------------------------------------------------------------
// Gather: xg[e][c][:] = bf16(x[tok]) or zeros. One block per slot.
// ---------------------------------------------------------------------------
__global__ __launch_bounds__(256) void gather_kernel(
    const float* __restrict__ x, const int* __restrict__ slot_tok, __bf16* __restrict__ xg)
{
    int s = blockIdx.x, tid = threadIdx.x;
    int tok = slot_tok[s];
    bf16x4 o;
    if (tok >= 0) {
        float4 v = *(const float4*)(x + (size_t)tok * HDIM + tid * 4);
        o[0] = (__bf16)v.x; o[1] = (__bf16)v.y; o[2] = (__bf16)v.z; o[3] = (__bf16)v.w;
    } else {
        o[0] = (__bf16)0.f; o[1] = (__bf16)0.f; o[2] = (__bf16)0.f; o[3] = (__bf16)0.f;
    }
    *(bf16x4*)(xg + (size_t)s * HDIM + tid * 4) = o;
}

// ---------------------------------------------------------------------------
// Transpose + fp32->bf16: in [e][R][Cc] -> out [e][Cc][R]. 64x64 LDS tiles.
// Row stride 68 keeps 8B alignment for b64 LDS writes and breaks pow2 conflicts.
// ---------------------------------------------------------------------------
__global__ __launch_bounds__(256) void transpose_cvt_kernel(
    const float* __restrict__ in, __bf16* __restrict__ out, int R, int Cc, int tilesR, int tilesC)
{
    __shared__ __bf16 tile[64][68];
    int bx = blockIdx.x;
    int tpe = tilesR * tilesC;
    int e = bx / tpe; int rem = bx - e * tpe;
    int tr = rem / tilesC; int tc = rem - tr * tilesC;
    const float* ine = in + (size_t)e * R * Cc;
    __bf16* oute = out + (size_t)e * R * Cc;
    int r0 = tr * 64, c0 = tc * 64;
    int tid = threadIdx.x;
    int rr = tid >> 4, c4 = (tid & 15) << 2;
#pragma unroll
    for (int it = 0; it < 4; ++it) {
        int r = rr + it * 16;
        float4 v = *(const float4*)(ine + (size_t)(r0 + r) * Cc + c0 + c4);
        tile[r][c4 + 0] = (__bf16)v.x; tile[r][c4 + 1] = (__bf16)v.y;
        tile[r][c4 + 2] = (__bf16)v.z; tile[r][c4 + 3] = (__bf16)v.w;
    }
    __syncthreads();
#pragma unroll
    for (int it = 0; it < 4; ++it) {
        int c = rr + it * 16;
        bf16x4 o;
        o[0] = tile[c4 + 0][c]; o[1] = tile[c4 + 1][c];
        o[2] = tile[c4 + 2][c]; o[3] = tile[c4 + 3][c];
        *(bf16x4*)(oute + (size_t)(c0 + c) * R + r0 + c4) = o;
    }
}

__global__ __launch_bounds__(256) void zero_kernel(float4* p)
{
    p[(size_t)blockIdx.x * 256 + threadIdx.x] = make_float4(0.f, 0.f, 0.f, 0.f);
}

// ---------------------------------------------------------------------------
// GEMM (m97-style): A [e][1024][Kd] bf16 k-contig, Bt [e][N][Kd] bf16 k-contig.
// 128x128 tile, BK=32, 4 waves, 4x4 mfma_f32_16x16x32_bf16 per wave.
// Staging: direct global_load_lds width-16 (m97/m151: 874 vs 646 TF reg-staged),
// double-buffered LDS, next k-tile issued BEFORE ds_read+MFMA (T3 2-phase min).
// EPI 0: bias + interleaved GLU -> act bf16 [e][1024][FDIM]
// EPI 1: bias, *slot_w, atomic scatter into out[tok][:]
// ---------------------------------------------------------------------------
template <int EPI>
__global__ __launch_bounds__(256) void gemm_kernel(
    const __bf16* __restrict__ A, const __bf16* __restrict__ Bt, const float* __restrict__ bias,
    __bf16* __restrict__ actout, float* __restrict__ out,
    const int* __restrict__ slot_tok, const float* __restrict__ slot_w,
    int Kd, int tilesM, int tilesN, int N)
{
    __shared__ __bf16 at[2][128 * 32];
    __shared__ __bf16 bts[2][128 * 32];
    int bx = blockIdx.x;
    int tpe = tilesM * tilesN;
    int e = bx / tpe; int rem = bx - e * tpe;
    int bm = rem / tilesN; int bn = rem - bm * tilesN;
    const __bf16* Ab = A + (size_t)e * 1024 * Kd + (size_t)(bm * 128) * Kd;
    const __bf16* Bb = Bt + (size_t)e * N * Kd + (size_t)(bn * 128) * Kd;
    int tid = threadIdx.x;
    // chunk c (c in [0,512)) = 16B at LDS byte c*16, global row c>>2, k-off (c&3)*8.
    // thread owns chunks tid and tid+256 (row+64, same k-off).
    int ar0 = tid >> 2, ak0 = (tid & 3) << 3;
    const __bf16* ga0 = Ab + (size_t)ar0 * Kd + ak0;
    const __bf16* ga1 = ga0 + (size_t)64 * Kd;
    const __bf16* gb0 = Bb + (size_t)ar0 * Kd + ak0;
    const __bf16* gb1 = gb0 + (size_t)64 * Kd;

    f32x4 zero4 = {0.f, 0.f, 0.f, 0.f};
    f32x4 acc[4][4];
#pragma unroll
    for (int mi = 0; mi < 4; ++mi)
#pragma unroll
        for (int ni = 0; ni < 4; ++ni) acc[mi][ni] = zero4;

    int w = tid >> 6, l = tid & 63;
    int q = l >> 4, ln = l & 15;
    int wr = (w >> 1) << 6, wc = (w & 1) << 6;

    int nk = Kd >> 5;
    // prologue: stage k-tile 0 into buffer 0 (async DMA; __syncthreads drains vmcnt)
    gload_lds16(ga0, &at[0][tid * 8]);
    gload_lds16(ga1, &at[0][(tid + 256) * 8]);
    gload_lds16(gb0, &bts[0][tid * 8]);
    gload_lds16(gb1, &bts[0][(tid + 256) * 8]);
    __syncthreads();

    int cur = 0;
    for (int t = 0; t < nk; ++t) {
        // issue next k-tile DMA first — overlaps with ds_read + MFMA below
        if (t + 1 < nk) {
            int ko = (t + 1) << 5;
            gload_lds16(ga0 + ko, &at[cur ^ 1][tid * 8]);
            gload_lds16(ga1 + ko, &at[cur ^ 1][(tid + 256) * 8]);
            gload_lds16(gb0 + ko, &bts[cur ^ 1][tid * 8]);
            gload_lds16(gb1 + ko, &bts[cur ^ 1][(tid + 256) * 8]);
        }
        bf16x8 af[4], bfr[4];
#pragma unroll
        for (int mi = 0; mi < 4; ++mi)
            af[mi] = *(const bf16x8*)(&at[cur][(wr + mi * 16 + ln) * 32 + q * 8]);
#pragma unroll
        for (int ni = 0; ni < 4; ++ni)
            bfr[ni] = *(const bf16x8*)(&bts[cur][(wc + ni * 16 + ln) * 32 + q * 8]);
#pragma unroll
        for (int mi = 0; mi < 4; ++mi)
#pragma unroll
            for (int ni = 0; ni < 4; ++ni)
                acc[mi][ni] = __builtin_amdgcn_mfma_f32_16x16x32_bf16(af[mi], bfr[ni], acc[mi][ni], 0, 0, 0);
        __syncthreads();   // drains vmcnt(0): next buffer ready; all reads of cur done
        cur ^= 1;
    }

    // C/D layout: col = lane&15, row = (lane>>4)*4 + reg   [m89-verified]
    float bv[4];
#pragma unroll
    for (int ni = 0; ni < 4; ++ni) bv[ni] = bias[(size_t)e * N + bn * 128 + wc + ni * 16 + ln];

    if constexpr (EPI == 0) {
        __bf16* act_e = actout + (size_t)e * 1024 * FDIM;
#pragma unroll
        for (int mi = 0; mi < 4; ++mi)
#pragma unroll
            for (int ni = 0; ni < 4; ++ni)
#pragma unroll
                for (int r = 0; r < 4; ++r) {
                    int m = bm * 128 + wr + mi * 16 + q * 4 + r;
                    int n = bn * 128 + wc + ni * 16 + ln;
                    float v = acc[mi][ni][r] + bv[ni];
                    float o = __shfl_xor(v, 1, 64);        // partner column (n^1)
                    float gate = (ln & 1) ? o : v;          // even col = gate
                    float up   = (ln & 1) ? v : o;          // odd col  = up
                    gate = fminf(gate, 7.f);
                    up = fminf(fmaxf(up, -7.f), 7.f);
                    float glu = gate / (1.f + __expf(-1.702f * gate));
                    float a = (up + 1.f) * glu;
                    if ((ln & 1) == 0) act_e[(size_t)m * FDIM + (n >> 1)] = (__bf16)a;
                }
    } else {
#pragma unroll
        for (int mi = 0; mi < 4; ++mi)
#pragma unroll
            for (int r = 0; r < 4; ++r) {
                int m = bm * 128 + wr + mi * 16 + q * 4 + r;
                int tok = slot_tok[e * CAP + m];
                float wgt = slot_w[e * CAP + m];
                if (tok >= 0) {
#pragma unroll
                    for (int ni = 0; ni < 4; ++ni) {
                        int n = bn * 128 + wc + ni * 16 + ln;
                        float v = (acc[mi][ni][r] + bv[ni]) * wgt;
                        unsafeAtomicAdd(out + (size_t)tok * HDIM + n, v);
                    }
                }
            }
    }
}

// ---------------------------------------------------------------------------
extern "C" void kernel_launch(void* const* d_in, const int* in_sizes, int n_in,
                              void* d_out, int out_size, void* d_ws, size_t ws_size,
                              hipStream_t stream)
{
    const float* x  = (const float*)d_in[0];
    const float* rw = (const float*)d_in[1];
    const float* rb = (const float*)d_in[2];
    const float* w1 = (const float*)d_in[3];
    const float* w2 = (const float*)d_in[4];
    const float* b1 = (const float*)d_in[5];
    const float* b2 = (const float*)d_in[6];
    float* out_main = (float*)d_out;                       // [T,H]
    float* ew_out = out_main + (size_t)T_TOK * HDIM;       // [T,4]
    float* rs_out = ew_out + (size_t)T_TOK * TOPK;         // [E,T]

    // Workspace layout (~302 MB total)
    char* ws = (char*)d_ws;
    size_t off = 0;
    auto alloc = [&](size_t bytes) { void* p = ws + off; off += (bytes + 255) & ~(size_t)255; return p; };
    __bf16* w1t = (__bf16*)alloc((size_t)E_EXP * 2 * FDIM * HDIM * 2);  // [E][2F][H] 134MB
    __bf16* w2t = (__bf16*)alloc((size_t)E_EXP * HDIM * FDIM * 2);      // [E][H][F]  67MB
    __bf16* xg  = (__bf16*)alloc((size_t)E_EXP * CAP * HDIM * 2);       // [E][C][H]  33.5MB
    __bf16* act = (__bf16*)alloc((size_t)E_EXP * CAP * FDIM * 2);       // [E][C][F]  67MB
    int*   te       = (int*)alloc((size_t)NCOPY * 4);
    int*   slot_tok = (int*)alloc((size_t)E_EXP * CAP * 4);
    float* slot_w   = (float*)alloc((size_t)E_EXP * CAP * 4);

    zero_kernel<<<(T_TOK * HDIM) / 1024, 256, 0, stream>>>((float4*)out_main);
    router_kernel<<<T_TOK, 64, 0, stream>>>(x, rw, rb, ew_out, rs_out, te);
    binning_kernel<<<1, 256, 0, stream>>>(te, ew_out, slot_tok, slot_w);
    gather_kernel<<<E_EXP * CAP, 256, 0, stream>>>(x, slot_tok, xg);
    transpose_cvt_kernel<<<E_EXP * (HDIM / 64) * (2 * FDIM / 64), 256, 0, stream>>>(
        w1, w1t, HDIM, 2 * FDIM, HDIM / 64, 2 * FDIM / 64);
    transpose_cvt_kernel<<<E_EXP * (FDIM / 64) * (HDIM / 64), 256, 0, stream>>>(
        w2, w2t, FDIM, HDIM, FDIM / 64, HDIM / 64);
    gemm_kernel<0><<<E_EXP * 8 * 32, 256, 0, stream>>>(
        xg, w1t, b1, act, nullptr, nullptr, nullptr, HDIM, 8, 32, 2 * FDIM);
    gemm_kernel<1><<<E_EXP * 8 * 8, 256, 0, stream>>>(
        act, w2t, b2, nullptr, out_main, slot_tok, slot_w, FDIM, 8, 8, HDIM);
}

// Round 2
// 874.603 us; speedup vs baseline: 1.0896x; 1.0896x over previous
//
#include <hip/hip_runtime.h>
#include <hip/hip_bf16.h>

// Problem constants (from reference)
#define T_TOK 4096      // SL*BS tokens
#define E_EXP 16
#define TOPK 4
#define HDIM 1024
#define FDIM 2048
#define CAP 1024        // capacity = K*T/E
#define NCOPY (T_TOK*TOPK)

typedef __bf16 bf16x8 __attribute__((ext_vector_type(8)));
typedef __bf16 bf16x4 __attribute__((ext_vector_type(4)));
typedef float  f32x4  __attribute__((ext_vector_type(4)));

// ---------------------------------------------------------------------------
// Router: logits = x @ rw^T + rb ; top-4 (desc, ties->lowest idx) ; softmax.
// One wave per token. Writes expert_weights [T,4], router_scores [E,T], te [T,4].
// ---------------------------------------------------------------------------
__global__ __launch_bounds__(64) void router_kernel(
    const float* __restrict__ x, const float* __restrict__ rw, const float* __restrict__ rb,
    float* __restrict__ ew_out, float* __restrict__ rs_out, int* __restrict__ te_out)
{
    int t = blockIdx.x;
    int lane = threadIdx.x;
    const float* xr = x + (size_t)t * HDIM;
    float xv[16];
#pragma unroll
    for (int i = 0; i < 16; ++i) xv[i] = xr[i * 64 + lane];
    float lg[E_EXP];
#pragma unroll
    for (int e = 0; e < E_EXP; ++e) {
        const float* wrow = rw + (size_t)e * HDIM;
        float s = 0.f;
#pragma unroll
        for (int i = 0; i < 16; ++i) s += xv[i] * wrow[i * 64 + lane];
#pragma unroll
        for (int off = 32; off > 0; off >>= 1) s += __shfl_xor(s, off, 64);
        lg[e] = s + rb[e];
    }
    // top-4, descending, strict '>' keeps lowest index on ties (matches lax.top_k)
    int mask = 0; float vals[4]; int idxs[4];
#pragma unroll
    for (int k = 0; k < 4; ++k) {
        float m = -3.4e38f; int a = 0;
#pragma unroll
        for (int e = 0; e < E_EXP; ++e) {
            bool take = (((mask >> e) & 1) == 0) && (lg[e] > m);
            m = take ? lg[e] : m;
            a = take ? e : a;
        }
        vals[k] = m; idxs[k] = a; mask |= (1 << a);
    }
    float wk[4]; float ssum = 0.f;
#pragma unroll
    for (int k = 0; k < 4; ++k) { wk[k] = __expf(vals[k] - vals[0]); ssum += wk[k]; }
    float inv = 1.f / ssum;
#pragma unroll
    for (int k = 0; k < 4; ++k) wk[k] *= inv;
    if (lane < 4) {
        float wv = 0.f; int iv = 0;
#pragma unroll
        for (int k = 0; k < 4; ++k) if (lane == k) { wv = wk[k]; iv = idxs[k]; }
        ew_out[t * 4 + lane] = wv;
        te_out[t * 4 + lane] = iv;
    }
    if (lane < E_EXP) {
        float v = 0.f;
#pragma unroll
        for (int k = 0; k < 4; ++k) v = (idxs[k] == lane) ? wk[k] : v;
        rs_out[(size_t)lane * T_TOK + t] = v;
    }
}

// ---------------------------------------------------------------------------
// Binning: stable rank-within-expert == stable argsort by expert id.
// Single block; thread owns 64 consecutive copies; chunked histogram + serial
// per-expert exclusive prefix over chunks. slot_tok=-1 marks empty slots.
// Also emits the inverse map copy_slot[idx] = e*CAP+rank (or -1 if dropped),
// consumed by combine_kernel (replaces the atomic scatter).
// ---------------------------------------------------------------------------
__global__ __launch_bounds__(256) void binning_kernel(
    const int* __restrict__ te,
    int* __restrict__ slot_tok, int* __restrict__ copy_slot)
{
    __shared__ int cnt[256][17];   // +1 pad: conflict-free columns
    int tid = threadIdx.x;
#pragma unroll
    for (int e = 0; e < E_EXP; ++e) cnt[tid][e] = 0;
    __syncthreads();
    int base = tid * 64;
    for (int i = 0; i < 64; ++i) cnt[tid][te[base + i]]++;
    __syncthreads();
    if (tid < E_EXP) {
        int run = 0;
        for (int t2 = 0; t2 < 256; ++t2) { int v = cnt[t2][tid]; cnt[t2][tid] = run; run += v; }
    }
    __syncthreads();
    for (int s = tid; s < E_EXP * CAP; s += 256) slot_tok[s] = -1;
    __syncthreads();
    for (int i = 0; i < 64; ++i) {
        int idx = base + i;
        int e = te[idx];
        int r = cnt[tid][e]; cnt[tid][e] = r + 1;
        if (r < CAP) { slot_tok[e * CAP + r] = idx >> 2; copy_slot[idx] = e * CAP + r; }
        else copy_slot[idx] = -1;
    }
}

// ---------------------------------------------------------------------------
// Gather: xg[e][c][:] = bf16(x[tok]) or zeros. One block per slot.
// ---------------------------------------------------------------------------
__global__ __launch_bounds__(256) void gather_kernel(
    const float* __restrict__ x, const int* __restrict__ slot_tok, __bf16* __restrict__ xg)
{
    int s = blockIdx.x, tid = threadIdx.x;
    int tok = slot_tok[s];
    bf16x4 o;
    if (tok >= 0) {
        float4 v = *(const float4*)(x + (size_t)tok * HDIM + tid * 4);
        o[0] = (__bf16)v.x; o[1] = (__bf16)v.y; o[2] = (__bf16)v.z; o[3] = (__bf16)v.w;
    } else {
        o[0] = (__bf16)0.f; o[1] = (__bf16)0.f; o[2] = (__bf16)0.f; o[3] = (__bf16)0.f;
    }
    *(bf16x4*)(xg + (size_t)s * HDIM + tid * 4) = o;
}

// ---------------------------------------------------------------------------
// Transpose + fp32->bf16: in [e][R][Cc] -> out [e][Cc][R]. 64x64 LDS tiles.
// Row stride 68 keeps 8B alignment for b64 LDS writes and breaks pow2 conflicts.
// ---------------------------------------------------------------------------
__global__ __launch_bounds__(256) void transpose_cvt_kernel(
    const float* __restrict__ in, __bf16* __restrict__ out, int R, int Cc, int tilesR, int tilesC)
{
    __shared__ __bf16 tile[64][68];
    int bx = blockIdx.x;
    int tpe = tilesR * tilesC;
    int e = bx / tpe; int rem = bx - e * tpe;
    int tr = rem / tilesC; int tc = rem - tr * tilesC;
    const float* ine = in + (size_t)e * R * Cc;
    __bf16* oute = out + (size_t)e * R * Cc;
    int r0 = tr * 64, c0 = tc * 64;
    int tid = threadIdx.x;
    int rr = tid >> 4, c4 = (tid & 15) << 2;
#pragma unroll
    for (int it = 0; it < 4; ++it) {
        int r = rr + it * 16;
        float4 v = *(const float4*)(ine + (size_t)(r0 + r) * Cc + c0 + c4);
        tile[r][c4 + 0] = (__bf16)v.x; tile[r][c4 + 1] = (__bf16)v.y;
        tile[r][c4 + 2] = (__bf16)v.z; tile[r][c4 + 3] = (__bf16)v.w;
    }
    __syncthreads();
#pragma unroll
    for (int it = 0; it < 4; ++it) {
        int c = rr + it * 16;
        bf16x4 o;
        o[0] = tile[c4 + 0][c]; o[1] = tile[c4 + 1][c];
        o[2] = tile[c4 + 2][c]; o[3] = tile[c4 + 3][c];
        *(bf16x4*)(oute + (size_t)(c0 + c) * R + r0 + c4) = o;
    }
}

// ---------------------------------------------------------------------------
// Combine: out[t] = sum_k ew[t,k] * ybuf[copy_slot[t,k]]. Replaces atomic
// scatter with a coalesced gather — each token row has <=4 contributors.
// ---------------------------------------------------------------------------
__global__ __launch_bounds__(256) void combine_kernel(
    const float* __restrict__ ybuf, const float* __restrict__ ew,
    const int* __restrict__ copy_slot, float* __restrict__ out)
{
    int t = blockIdx.x, tid = threadIdx.x;
    float4 acc = make_float4(0.f, 0.f, 0.f, 0.f);
#pragma unroll
    for (int k = 0; k < 4; ++k) {
        int s = copy_slot[t * 4 + k];
        float wk = ew[t * 4 + k];
        if (s >= 0) {
            float4 v = *(const float4*)(ybuf + (size_t)s * HDIM + tid * 4);
            acc.x += wk * v.x; acc.y += wk * v.y;
            acc.z += wk * v.z; acc.w += wk * v.w;
        }
    }
    *(float4*)(out + (size_t)t * HDIM + tid * 4) = acc;
}

// ---------------------------------------------------------------------------
// GEMM (round-0 verified): A [e][1024][Kd] bf16 k-contig, Bt [e][N][Kd] bf16
// k-contig. 128x128 tile, BK=32, 4 waves, 4x4 mfma_f32_16x16x32_bf16 per wave.
// Register-staged global->LDS, software-pipelined one k-step ahead.
// EPI 0: bias + interleaved GLU -> act bf16 [e][1024][FDIM]
// EPI 1: bias -> plain fp32 store into ybuf [e][CAP][N] (no atomics)
// ---------------------------------------------------------------------------
template <int EPI>
__global__ __launch_bounds__(256) void gemm_kernel(
    const __bf16* __restrict__ A, const __bf16* __restrict__ Bt, const float* __restrict__ bias,
    __bf16* __restrict__ actout, float* __restrict__ out,
    int Kd, int tilesM, int tilesN, int N)
{
    __shared__ __bf16 at[128 * 32];
    __shared__ __bf16 bts[128 * 32];
    int bx = blockIdx.x;
    int tpe = tilesM * tilesN;
    int e = bx / tpe; int rem = bx - e * tpe;
    int bm = rem / tilesN; int bn = rem - bm * tilesN;
    const __bf16* Ab = A + (size_t)e * 1024 * Kd + (size_t)(bm * 128) * Kd;
    const __bf16* Bb = Bt + (size_t)e * N * Kd + (size_t)(bn * 128) * Kd;
    int tid = threadIdx.x;
    int c0 = tid, c1 = tid + 256;
    int ar0 = c0 >> 2, ak0 = (c0 & 3) << 3;
    int ar1 = c1 >> 2, ak1 = (c1 & 3) << 3;

    uint4 ra0 = *(const uint4*)(Ab + (size_t)ar0 * Kd + ak0);
    uint4 ra1 = *(const uint4*)(Ab + (size_t)ar1 * Kd + ak1);
    uint4 rb0 = *(const uint4*)(Bb + (size_t)ar0 * Kd + ak0);
    uint4 rb1 = *(const uint4*)(Bb + (size_t)ar1 * Kd + ak1);

    f32x4 zero4 = {0.f, 0.f, 0.f, 0.f};
    f32x4 acc[4][4];
#pragma unroll
    for (int mi = 0; mi < 4; ++mi)
#pragma unroll
        for (int ni = 0; ni < 4; ++ni) acc[mi][ni] = zero4;

    int w = tid >> 6, l = tid & 63;
    int q = l >> 4, ln = l & 15;
    int wr = (w >> 1) << 6, wc = (w & 1) << 6;

    for (int k0 = 0; k0 < Kd; k0 += 32) {
        *(uint4*)(at + c0 * 8) = ra0;
        *(uint4*)(at + c1 * 8) = ra1;
        *(uint4*)(bts + c0 * 8) = rb0;
        *(uint4*)(bts + c1 * 8) = rb1;
        int kn = k0 + 32;
        if (kn < Kd) {  // prefetch next k-tile into registers while MFMA runs
            ra0 = *(const uint4*)(Ab + (size_t)ar0 * Kd + kn + ak0);
            ra1 = *(const uint4*)(Ab + (size_t)ar1 * Kd + kn + ak1);
            rb0 = *(const uint4*)(Bb + (size_t)ar0 * Kd + kn + ak0);
            rb1 = *(const uint4*)(Bb + (size_t)ar1 * Kd + kn + ak1);
        }
        __syncthreads();
        bf16x8 af[4], bfr[4];
#pragma unroll
        for (int mi = 0; mi < 4; ++mi)
            af[mi] = *(const bf16x8*)(at + (wr + mi * 16 + ln) * 32 + q * 8);
#pragma unroll
        for (int ni = 0; ni < 4; ++ni)
            bfr[ni] = *(const bf16x8*)(bts + (wc + ni * 16 + ln) * 32 + q * 8);
#pragma unroll
        for (int mi = 0; mi < 4; ++mi)
#pragma unroll
            for (int ni = 0; ni < 4; ++ni)
                acc[mi][ni] = __builtin_amdgcn_mfma_f32_16x16x32_bf16(af[mi], bfr[ni], acc[mi][ni], 0, 0, 0);
        __syncthreads();
    }

    // C/D layout: col = lane&15, row = (lane>>4)*4 + reg   [m89-verified]
    float bv[4];
#pragma unroll
    for (int ni = 0; ni < 4; ++ni) bv[ni] = bias[(size_t)e * N + bn * 128 + wc + ni * 16 + ln];

    if constexpr (EPI == 0) {
        __bf16* act_e = actout + (size_t)e * 1024 * FDIM;
#pragma unroll
        for (int mi = 0; mi < 4; ++mi)
#pragma unroll
            for (int ni = 0; ni < 4; ++ni)
#pragma unroll
                for (int r = 0; r < 4; ++r) {
                    int m = bm * 128 + wr + mi * 16 + q * 4 + r;
                    int n = bn * 128 + wc + ni * 16 + ln;
                    float v = acc[mi][ni][r] + bv[ni];
                    float o = __shfl_xor(v, 1, 64);        // partner column (n^1)
                    float gate = (ln & 1) ? o : v;          // even col = gate
                    float up   = (ln & 1) ? v : o;          // odd col  = up
                    gate = fminf(gate, 7.f);
                    up = fminf(fmaxf(up, -7.f), 7.f);
                    float glu = gate / (1.f + __expf(-1.702f * gate));
                    float a = (up + 1.f) * glu;
                    if ((ln & 1) == 0) act_e[(size_t)m * FDIM + (n >> 1)] = (__bf16)a;
                }
    } else {
        // plain stores of y+bias into ybuf [e][CAP][N]; combine_kernel applies
        // the routing weights and sums per token (no device-scope atomics).
        float* ye = out + (size_t)e * CAP * N;
#pragma unroll
        for (int mi = 0; mi < 4; ++mi)
#pragma unroll
            for (int r = 0; r < 4; ++r) {
                int m = bm * 128 + wr + mi * 16 + q * 4 + r;
#pragma unroll
                for (int ni = 0; ni < 4; ++ni) {
                    int n = bn * 128 + wc + ni * 16 + ln;
                    ye[(size_t)m * N + n] = acc[mi][ni][r] + bv[ni];
                }
            }
    }
}

// ---------------------------------------------------------------------------
extern "C" void kernel_launch(void* const* d_in, const int* in_sizes, int n_in,
                              void* d_out, int out_size, void* d_ws, size_t ws_size,
                              hipStream_t stream)
{
    const float* x  = (const float*)d_in[0];
    const float* rw = (const float*)d_in[1];
    const float* rb = (const float*)d_in[2];
    const float* w1 = (const float*)d_in[3];
    const float* w2 = (const float*)d_in[4];
    const float* b1 = (const float*)d_in[5];
    const float* b2 = (const float*)d_in[6];
    float* out_main = (float*)d_out;                       // [T,H]
    float* ew_out = out_main + (size_t)T_TOK * HDIM;       // [T,4]
    float* rs_out = ew_out + (size_t)T_TOK * TOPK;         // [E,T]

    // Workspace layout (~302 MB total)
    char* ws = (char*)d_ws;
    size_t off = 0;
    auto alloc = [&](size_t bytes) { void* p = ws + off; off += (bytes + 255) & ~(size_t)255; return p; };
    __bf16* w1t = (__bf16*)alloc((size_t)E_EXP * 2 * FDIM * HDIM * 2);  // [E][2F][H] 134MB
    __bf16* w2t = (__bf16*)alloc((size_t)E_EXP * HDIM * FDIM * 2);      // [E][H][F]  67MB
    __bf16* xg  = (__bf16*)alloc((size_t)E_EXP * CAP * HDIM * 2);       // [E][C][H]  33.5MB
    __bf16* act = (__bf16*)alloc((size_t)E_EXP * CAP * FDIM * 2);       // [E][C][F]  67MB
    int*   te       = (int*)alloc((size_t)NCOPY * 4);
    int*   slot_tok = (int*)alloc((size_t)E_EXP * CAP * 4);
    int*   copy_slot= (int*)alloc((size_t)NCOPY * 4);
    // ybuf (67MB fp32) aliases the w1t region: w1t is dead after gemm<0> reads
    // it, and gemm<1> (which writes ybuf) only starts after gemm<0> completes.
    float* ybuf = (float*)w1t;

    router_kernel<<<T_TOK, 64, 0, stream>>>(x, rw, rb, ew_out, rs_out, te);
    binning_kernel<<<1, 256, 0, stream>>>(te, slot_tok, copy_slot);
    gather_kernel<<<E_EXP * CAP, 256, 0, stream>>>(x, slot_tok, xg);
    transpose_cvt_kernel<<<E_EXP * (HDIM / 64) * (2 * FDIM / 64), 256, 0, stream>>>(
        w1, w1t, HDIM, 2 * FDIM, HDIM / 64, 2 * FDIM / 64);
    transpose_cvt_kernel<<<E_EXP * (FDIM / 64) * (HDIM / 64), 256, 0, stream>>>(
        w2, w2t, FDIM, HDIM, FDIM / 64, HDIM / 64);
    gemm_kernel<0><<<E_EXP * 8 * 32, 256, 0, stream>>>(
        xg, w1t, b1, act, nullptr, HDIM, 8, 32, 2 * FDIM);
    gemm_kernel<1><<<E_EXP * 8 * 8, 256, 0, stream>>>(
        act, w2t, b2, nullptr, ybuf, FDIM, 8, 8, HDIM);
    combine_kernel<<<T_TOK, 256, 0, stream>>>(ybuf, ew_out, copy_slot, out_main);
}